// Round 2
// baseline (3874.609 us; speedup 1.0000x reference)
//
#include <hip/hip_runtime.h>

// ---------------------------------------------------------------------------
// ManualLSTM: B=32, S=512, H=1024.
//   Phase A: xg = bf16(x) @ bf16(Wi)  -> bf16 [16384][4096]  (bias in phase B)
//   Phase B (R8): persistent recurrence, 2 groups x 64 blocks (128 blocks --
//     2x CU-residency margin vs R7's 256; all MFMA rows now REAL, no mirror).
//     - Group g owns batches 16g..16g+15, full 4096-gate dim; block m owns
//       hidden cols m*16..+16 (64 gate cols).
//     - Wh slice pinned in VGPRs (32 bf16x8 frags/lane). No W in LDS.
//     - h exchange via NEVER-REUSED ring (512 slots x 2 groups x 32KB = 32MB,
//       lives in the dead xb region => ws footprint unchanged). Producers: 8B
//       agent-scope (LLC) atomic stores (shfl-packed). Consumers: PLAIN
//       global_load_dwordx4 straight into MFMA A-frags -- each ring address
//       is written once and read once, so no stale L1/L2 copy can exist
//       (xb-era lines are invalidated by the dispatch-boundary acquire, the
//       same mechanism that makes xg readable).
//     - LDS = 4KB gates only. Ordering: stores -> vmcnt(0) -> barrier ->
//       relaxed flag (R3/R6-validated protocol, unchanged).
// ---------------------------------------------------------------------------

typedef __attribute__((ext_vector_type(4))) float f32x4_t;
typedef __attribute__((ext_vector_type(8))) short bf16x8_t;
typedef unsigned long long ull_t;

#define HID   1024
#define SLEN  512
#define NGATE 4096

// ws layout (bytes)
#define XG_OFF    0ULL                      // 16384*4096*2 = 134217728
#define RING_OFF  134217728ULL              // 512*2*32768  = 33554432 (old xb)
#define WIT_OFF   167772160ULL              // 4096*1024*2  = 8388608
#define WHT_OFF   176160768ULL              // 4096*1024*2  = 8388608
#define FLAGS_OFF 184680448ULL              // 128 flags * 16B stride
// xb (phase-A bf16 x) shares the RING region: gemm_xg reads it fully before
// lstm_persistent writes the ring (same stream, sequential dispatches).
#define XB_OFF    RING_OFF

#define NBLK_B      128                     // 2 groups x 64 blocks
#define FLAG_STRIDE 4                       // dwords (16B)
#define SLOT_SHORTS 32768                   // 2 groups * 16384 shorts = 64KB

__device__ __forceinline__ unsigned short f2bf(float f) {
  unsigned u = __float_as_uint(f);
  u += 0x7fffu + ((u >> 16) & 1u);          // round-nearest-even
  return (unsigned short)(u >> 16);
}
__device__ __forceinline__ float bf2f(unsigned short u) {
  return __uint_as_float(((unsigned)u) << 16);
}
__device__ __forceinline__ float fast_rcp(float x) { return __builtin_amdgcn_rcpf(x); }
__device__ __forceinline__ float sigmoid_f(float x) { return fast_rcp(1.f + __expf(-x)); }
__device__ __forceinline__ float tanh_f(float x) { return 1.f - 2.f * fast_rcp(1.f + __expf(2.f * x)); }

// ---------------------------------------------------------------- converters
__global__ __launch_bounds__(256) void conv_x_bf16(const float* __restrict__ in,
                                                   unsigned short* __restrict__ out) {
  size_t i = (size_t)blockIdx.x * 256 + threadIdx.x;
  const float4* p = (const float4*)in;
  float4 v = p[i];
  ushort4 o;
  o.x = f2bf(v.x); o.y = f2bf(v.y); o.z = f2bf(v.z); o.w = f2bf(v.w);
  ((ushort4*)out)[i] = o;
}

// in: fp32 [1024][4096]  -> out: bf16 [4096][1024]  (out[n][k] = in[k][n])
__global__ void transpose_w_bf16(const float* __restrict__ in,
                                 unsigned short* __restrict__ out) {
  __shared__ float tile[32][33];
  int tx = threadIdx.x, ty = threadIdx.y;        // block (32, 8)
  int n0 = blockIdx.x * 32, k0 = blockIdx.y * 32;
  #pragma unroll
  for (int i = 0; i < 4; i++)
    tile[ty + 8 * i][tx] = in[(size_t)(k0 + ty + 8 * i) * NGATE + n0 + tx];
  __syncthreads();
  #pragma unroll
  for (int i = 0; i < 4; i++)
    out[(size_t)(n0 + ty + 8 * i) * HID + k0 + tx] = f2bf(tile[tx][ty + 8 * i]);
}

__global__ void init_ws(unsigned* __restrict__ flags) {
  int i = (int)blockIdx.x * 256 + threadIdx.x;
  if (i < NBLK_B * FLAG_STRIDE) flags[i] = 0u;
}

// ---------------------------------------------------------------- Phase A
// C[16384][4096] bf16 = A[16384][1024] bf16  x  BT[4096][1024] bf16
__global__ __launch_bounds__(256) void gemm_xg(const unsigned short* __restrict__ A,
                                               const unsigned short* __restrict__ BT,
                                               unsigned short* __restrict__ C) {
  extern __shared__ char smem[];
  char* As = smem;                 // 128 rows * 80B (32 bf16 + 16B pad)
  char* Bs = smem + 10240;
  const int tid = threadIdx.x;
  const int lane = tid & 63, w = tid >> 6, q = lane >> 4, l16 = lane & 15;
  const int wm = w & 1, wn = w >> 1;
  const size_t m0 = (size_t)blockIdx.y * 128, n0 = (size_t)blockIdx.x * 128;

  f32x4_t acc[4][4];
  #pragma unroll
  for (int i = 0; i < 4; i++)
    #pragma unroll
    for (int j = 0; j < 4; j++) acc[i][j] = (f32x4_t){0.f, 0.f, 0.f, 0.f};

  for (int kk = 0; kk < 32; kk++) {
    const int k0 = kk * 32;
    #pragma unroll
    for (int h = 0; h < 2; h++) {
      int idx = tid + h * 256;              // 0..511
      int r = idx >> 2, ch = idx & 3;
      uint4 va = *(const uint4*)((const char*)A + ((m0 + r) * HID + k0) * 2 + ch * 16);
      *(uint4*)(As + r * 80 + ch * 16) = va;
      uint4 vb = *(const uint4*)((const char*)BT + ((n0 + r) * HID + k0) * 2 + ch * 16);
      *(uint4*)(Bs + r * 80 + ch * 16) = vb;
    }
    __syncthreads();
    bf16x8_t af[4], bf[4];
    #pragma unroll
    for (int mt = 0; mt < 4; mt++)
      af[mt] = *(const bf16x8_t*)(As + (wm * 64 + mt * 16 + l16) * 80 + q * 16);
    #pragma unroll
    for (int nt = 0; nt < 4; nt++)
      bf[nt] = *(const bf16x8_t*)(Bs + (wn * 64 + nt * 16 + l16) * 80 + q * 16);
    #pragma unroll
    for (int mt = 0; mt < 4; mt++)
      #pragma unroll
      for (int nt = 0; nt < 4; nt++)
        acc[mt][nt] = __builtin_amdgcn_mfma_f32_16x16x32_bf16(af[mt], bf[nt], acc[mt][nt], 0, 0, 0);
    __syncthreads();
  }

  // epilogue: stage C tile (bf16 [128][136]) through LDS for coalesced stores
  unsigned short* cst = (unsigned short*)smem;
  #pragma unroll
  for (int mt = 0; mt < 4; mt++)
    #pragma unroll
    for (int nt = 0; nt < 4; nt++)
      #pragma unroll
      for (int r = 0; r < 4; r++) {
        int m = wm * 64 + mt * 16 + q * 4 + r;
        int n = wn * 64 + nt * 16 + l16;
        cst[m * 136 + n] = f2bf(acc[mt][nt][r]);
      }
  __syncthreads();
  #pragma unroll
  for (int i = 0; i < 8; i++) {
    int idx = tid + i * 256;                // < 2048
    int row = idx >> 4, ch = idx & 15;
    uint4 v = *(const uint4*)((const char*)cst + row * 272 + ch * 16);
    *(uint4*)((char*)C + ((m0 + row) * NGATE + n0) * 2 + ch * 16) = v;
  }
}

// ---------------------------------------------------------------- Phase B
// 2 groups x 64 blocks x 256 threads. Group = 16 batches, full gate dim.
// Block m: hidden cols m*16..+16; wave wv = gate group G (i/f/g/o).
#define LD8(dst, base_kk)                                                     \
  _Pragma("unroll")                                                           \
  for (int i_ = 0; i_ < 8; i_++)                                              \
    dst[i_] = *(const bf16x8_t*)(ab + (base_kk) * 64 + i_ * 64);

#define FM8(src, base_kk)                                                     \
  _Pragma("unroll")                                                           \
  for (int i_ = 0; i_ < 4; i_++) {                                            \
    acc0 = __builtin_amdgcn_mfma_f32_16x16x32_bf16(src[2 * i_],               \
             bfr[(base_kk) + 2 * i_], acc0, 0, 0, 0);                         \
    acc1 = __builtin_amdgcn_mfma_f32_16x16x32_bf16(src[2 * i_ + 1],           \
             bfr[(base_kk) + 2 * i_ + 1], acc1, 0, 0, 0);                     \
  }

__global__ __launch_bounds__(256, 1) void lstm_persistent(
    const unsigned short* __restrict__ xg,   // [16384][4096] bf16
    const unsigned short* __restrict__ whT,  // [4096][1024] bf16
    const float* __restrict__ bias,          // [4096]
    float* __restrict__ out,                 // [32][512][1024]
    unsigned short* ring,                    // 512 slots x 2 groups x [16][1024] bf16
    unsigned* flags) {                       // 128 @ 16B stride, group-major
  __shared__ float gates[16 * 65];           // [16 batch][65] f32

  const int tid = threadIdx.x;
  const int lane = tid & 63, wv = tid >> 6, q = lane >> 4, l16 = lane & 15;
  const int g = blockIdx.x >> 6;                   // group 0..1
  const int m = blockIdx.x & 63;                   // member 0..63
  const int b_e = tid >> 4, j_e = tid & 15;        // EW mapping (all 256)

  // pin Wh B-fragments in VGPRs: wave wv owns gate cols wv*1024 + m*16 + l16.
  // B-frag kk: lane (l16=col, q=k-octet) reads whT row, bytes q*16 + kk*64.
  bf16x8_t bfr[32];
  {
    const char* wrow = (const char*)whT +
        ((size_t)(wv * 1024 + m * 16 + l16) * HID) * 2 + q * 16;
    #pragma unroll
    for (int kk = 0; kk < 32; kk++)
      bfr[kk] = *(const bf16x8_t*)(wrow + kk * 64);
  }
  float bsr[4];
  #pragma unroll
  for (int G = 0; G < 4; G++) bsr[G] = bias[G * 1024 + m * 16 + j_e];
  float c_st = 0.f;
  unsigned short* ring_g = ring + (size_t)g * 16384;   // 32KB group image
  unsigned* fl_g = flags + g * 64 * FLAG_STRIDE;
  const int a_off = l16 * 2048 + q * 16;               // bytes in [16][2048B]

  for (int t = 0; t < SLEN; t++) {
    // xg prefetch (no h dependency) — overlaps the flag wait
    const unsigned short* p =
        xg + ((size_t)(g * 16 + b_e) * 512 + t) * 4096 + m * 16 + j_e;
    unsigned short xgv0 = p[0], xgv1 = p[1024], xgv2 = p[2048], xgv3 = p[3072];

    f32x4_t acc0 = (f32x4_t){0.f, 0.f, 0.f, 0.f};
    f32x4_t acc1 = (f32x4_t){0.f, 0.f, 0.f, 0.f};
    if (t > 0) {
      if (tid < 64) {
        const unsigned* fp = fl_g + tid * FLAG_STRIDE;
        while (__hip_atomic_load(fp, __ATOMIC_RELAXED, __HIP_MEMORY_SCOPE_AGENT) < (unsigned)t)
          __builtin_amdgcn_s_sleep(1);
      }
      __syncthreads();
      asm volatile("" ::: "memory");
      // A-frags straight from ring slot t-1 (plain cached loads: slot
      // addresses are virgin -> no stale L1/L2 possible; producers wrote LLC)
      const char* ab = (const char*)(ring_g + (size_t)(t - 1) * SLOT_SHORTS) + a_off;
      bf16x8_t af0[8], af1[8], af2[8], af3[8];
      LD8(af0, 0);  LD8(af1, 8);
      FM8(af0, 0);  LD8(af2, 16);
      FM8(af1, 8);  LD8(af3, 24);
      FM8(af2, 16); FM8(af3, 24);
    }
    #pragma unroll
    for (int r = 0; r < 4; r++)
      gates[(q * 4 + r) * 65 + wv * 16 + l16] = acc0[r] + acc1[r];
    __syncthreads();

    // elementwise: 256 threads own (b_e, j_e)
    {
      float gi = gates[b_e * 65 + j_e]      + bsr[0] + bf2f(xgv0);
      float gf = gates[b_e * 65 + 16 + j_e] + bsr[1] + bf2f(xgv1);
      float gg = gates[b_e * 65 + 32 + j_e] + bsr[2] + bf2f(xgv2);
      float go = gates[b_e * 65 + 48 + j_e] + bsr[3] + bf2f(xgv3);
      float i_s = sigmoid_f(gi), f_s = sigmoid_f(gf);
      float g_t = tanh_f(gg), o_s = sigmoid_f(go);
      c_st = f_s * c_st + i_s * g_t;
      float h = o_s * tanh_f(c_st);
      // pack 4 cols into 8B via two shuffles; lanes j%4==0 store LLC-direct
      unsigned short hb = f2bf(h);
      unsigned other = __shfl_xor((unsigned)hb, 1);
      unsigned u = ((unsigned)hb & 0xffffu) | (other << 16);   // cols j, j+1
      unsigned u2 = __shfl_xor(u, 2);                          // cols j+2, j+3
      if ((j_e & 3) == 0) {
        ull_t v8 = (ull_t)u | ((ull_t)u2 << 32);
        ull_t* dst = (ull_t*)(ring_g + (size_t)t * SLOT_SHORTS +
                              b_e * 1024 + m * 16 + j_e);
        __hip_atomic_store(dst, v8, __ATOMIC_RELAXED, __HIP_MEMORY_SCOPE_AGENT);
      }
      out[((size_t)(g * 16 + b_e) * 512 + t) * 1024 + m * 16 + j_e] = h;
    }
    // drain own wave's stores; barrier = all waves drained; then flag
    asm volatile("s_waitcnt vmcnt(0)" ::: "memory");
    __syncthreads();
    if (tid == 0)
      __hip_atomic_store(fl_g + m * FLAG_STRIDE, (unsigned)(t + 1),
                         __ATOMIC_RELAXED, __HIP_MEMORY_SCOPE_AGENT);
  }
}

// ---------------------------------------------------------------- launcher
extern "C" void kernel_launch(void* const* d_in, const int* in_sizes, int n_in,
                              void* d_out, int out_size, void* d_ws, size_t ws_size,
                              hipStream_t stream) {
  const float* x    = (const float*)d_in[0];   // [32,512,1024]
  const float* wi   = (const float*)d_in[1];   // [1024,4096]
  const float* wh   = (const float*)d_in[2];   // [1024,4096]
  const float* bias = (const float*)d_in[3];   // [4096]
  float* out = (float*)d_out;

  char* ws = (char*)d_ws;
  unsigned short* xg   = (unsigned short*)(ws + XG_OFF);
  unsigned short* xb   = (unsigned short*)(ws + XB_OFF);   // dead after gemm_xg
  unsigned short* ring = (unsigned short*)(ws + RING_OFF); // overlays xb
  unsigned short* wiT  = (unsigned short*)(ws + WIT_OFF);
  unsigned short* whT  = (unsigned short*)(ws + WHT_OFF);
  unsigned* flags      = (unsigned*)(ws + FLAGS_OFF);

  conv_x_bf16<<<16384, 256, 0, stream>>>(x, xb);
  transpose_w_bf16<<<dim3(128, 32), dim3(32, 8), 0, stream>>>(wi, wiT);
  transpose_w_bf16<<<dim3(128, 32), dim3(32, 8), 0, stream>>>(wh, whT);
  init_ws<<<2, 256, 0, stream>>>(flags);
  gemm_xg<<<dim3(32, 128), 256, 34816, stream>>>(xb, wiT, xg);
  lstm_persistent<<<NBLK_B, 256, 0, stream>>>(xg, whT, bias, out, ring, flags);
}

// Round 3
// 2197.427 us; speedup vs baseline: 1.7632x; 1.7632x over previous
//
#include <hip/hip_runtime.h>

// ---------------------------------------------------------------------------
// ManualLSTM: B=32, S=512, H=1024.
//   Phase A: xg = bf16(x) @ bf16(Wi)  -> bf16 [16384][4096]  (bias in phase B)
//   Phase B (R9 = R6 skeleton + R8 transport): persistent recurrence,
//     4 groups x 64 blocks. Group g owns batches 8g..8g+7 + full gate dim;
//     block m owns hidden cols m*16..+16 (64 gate cols, Wh slice in LDS).
//     - h exchange via NEVER-REUSED ring (512 slots x 4 groups x 16KB = 32MB,
//       overlays dead xb region). Producers: shfl-packed 8B agent-scope (LLC)
//       atomic stores (32/block, was 128x2B). Consumers: PLAIN coalesced
//       global_load_dwordx4 (lane-contiguous 1KB/instr) into the LDS image --
//       ring addresses are written once / read once, so no stale L1/L2 copy
//       can exist (R8-validated). Kills the 512K-atomic/step LLC gather storm
//       while keeping R6's cheap LDS-fed MFMA path.
//     - Sync: stores -> vmcnt(0) -> barrier -> relaxed flag; consumer polls
//       64 flags (R3/R6-validated protocol, unchanged).
// ---------------------------------------------------------------------------

typedef __attribute__((ext_vector_type(4))) float f32x4_t;
typedef __attribute__((ext_vector_type(8))) short bf16x8_t;
typedef unsigned long long ull_t;

#define HID   1024
#define SLEN  512
#define NGATE 4096

// ws layout (bytes)
#define XG_OFF    0ULL                      // 16384*4096*2 = 134217728
#define RING_OFF  134217728ULL              // 512*4*16384  = 33554432 (old xb)
#define WIT_OFF   167772160ULL              // 4096*1024*2  = 8388608
#define WHT_OFF   176160768ULL              // 4096*1024*2  = 8388608
#define FLAGS_OFF 184680448ULL              // 256 flags * 16B stride = 4096B
// xb (phase-A bf16 x) shares the RING region: gemm_xg reads it fully before
// lstm_persistent writes the ring (same stream, sequential dispatches).
#define XB_OFF    RING_OFF

#define NBLK_B      256                     // 4 groups x 64 blocks
#define FLAG_STRIDE 4                       // dwords (16B)
#define SLOT_SHORTS 32768                   // 4 groups * 8192 shorts = 64KB/slot

// persistent-kernel LDS layout
#define W_OFF_L   0                         // 64 rows * 2064B = 132096
#define H_OFF_L   132096                    // 8 rows * 2064B  = 16512
#define G_OFF_L   148608                    // gates [16][65] f32 = 4160
#define LDS_TOTAL 152768

__device__ __forceinline__ unsigned short f2bf(float f) {
  unsigned u = __float_as_uint(f);
  u += 0x7fffu + ((u >> 16) & 1u);          // round-nearest-even
  return (unsigned short)(u >> 16);
}
__device__ __forceinline__ float bf2f(unsigned short u) {
  return __uint_as_float(((unsigned)u) << 16);
}
__device__ __forceinline__ float fast_rcp(float x) { return __builtin_amdgcn_rcpf(x); }
__device__ __forceinline__ float sigmoid_f(float x) { return fast_rcp(1.f + __expf(-x)); }
__device__ __forceinline__ float tanh_f(float x) { return 1.f - 2.f * fast_rcp(1.f + __expf(2.f * x)); }

// ---------------------------------------------------------------- converters
__global__ __launch_bounds__(256) void conv_x_bf16(const float* __restrict__ in,
                                                   unsigned short* __restrict__ out) {
  size_t i = (size_t)blockIdx.x * 256 + threadIdx.x;
  const float4* p = (const float4*)in;
  float4 v = p[i];
  ushort4 o;
  o.x = f2bf(v.x); o.y = f2bf(v.y); o.z = f2bf(v.z); o.w = f2bf(v.w);
  ((ushort4*)out)[i] = o;
}

// in: fp32 [1024][4096]  -> out: bf16 [4096][1024]  (out[n][k] = in[k][n])
__global__ void transpose_w_bf16(const float* __restrict__ in,
                                 unsigned short* __restrict__ out) {
  __shared__ float tile[32][33];
  int tx = threadIdx.x, ty = threadIdx.y;        // block (32, 8)
  int n0 = blockIdx.x * 32, k0 = blockIdx.y * 32;
  #pragma unroll
  for (int i = 0; i < 4; i++)
    tile[ty + 8 * i][tx] = in[(size_t)(k0 + ty + 8 * i) * NGATE + n0 + tx];
  __syncthreads();
  #pragma unroll
  for (int i = 0; i < 4; i++)
    out[(size_t)(n0 + ty + 8 * i) * HID + k0 + tx] = f2bf(tile[tx][ty + 8 * i]);
}

__global__ void init_ws(unsigned* __restrict__ flags) {
  int i = (int)blockIdx.x * 256 + threadIdx.x;   // 1024 threads
  if (i < NBLK_B * FLAG_STRIDE) flags[i] = 0u;
}

// ---------------------------------------------------------------- Phase A
// C[16384][4096] bf16 = A[16384][1024] bf16  x  BT[4096][1024] bf16
__global__ __launch_bounds__(256) void gemm_xg(const unsigned short* __restrict__ A,
                                               const unsigned short* __restrict__ BT,
                                               unsigned short* __restrict__ C) {
  extern __shared__ char smem[];
  char* As = smem;                 // 128 rows * 80B (32 bf16 + 16B pad)
  char* Bs = smem + 10240;
  const int tid = threadIdx.x;
  const int lane = tid & 63, w = tid >> 6, q = lane >> 4, l16 = lane & 15;
  const int wm = w & 1, wn = w >> 1;
  const size_t m0 = (size_t)blockIdx.y * 128, n0 = (size_t)blockIdx.x * 128;

  f32x4_t acc[4][4];
  #pragma unroll
  for (int i = 0; i < 4; i++)
    #pragma unroll
    for (int j = 0; j < 4; j++) acc[i][j] = (f32x4_t){0.f, 0.f, 0.f, 0.f};

  for (int kk = 0; kk < 32; kk++) {
    const int k0 = kk * 32;
    #pragma unroll
    for (int h = 0; h < 2; h++) {
      int idx = tid + h * 256;              // 0..511
      int r = idx >> 2, ch = idx & 3;
      uint4 va = *(const uint4*)((const char*)A + ((m0 + r) * HID + k0) * 2 + ch * 16);
      *(uint4*)(As + r * 80 + ch * 16) = va;
      uint4 vb = *(const uint4*)((const char*)BT + ((n0 + r) * HID + k0) * 2 + ch * 16);
      *(uint4*)(Bs + r * 80 + ch * 16) = vb;
    }
    __syncthreads();
    bf16x8_t af[4], bf[4];
    #pragma unroll
    for (int mt = 0; mt < 4; mt++)
      af[mt] = *(const bf16x8_t*)(As + (wm * 64 + mt * 16 + l16) * 80 + q * 16);
    #pragma unroll
    for (int nt = 0; nt < 4; nt++)
      bf[nt] = *(const bf16x8_t*)(Bs + (wn * 64 + nt * 16 + l16) * 80 + q * 16);
    #pragma unroll
    for (int mt = 0; mt < 4; mt++)
      #pragma unroll
      for (int nt = 0; nt < 4; nt++)
        acc[mt][nt] = __builtin_amdgcn_mfma_f32_16x16x32_bf16(af[mt], bf[nt], acc[mt][nt], 0, 0, 0);
    __syncthreads();
  }

  // epilogue: stage C tile (bf16 [128][136]) through LDS for coalesced stores
  unsigned short* cst = (unsigned short*)smem;
  #pragma unroll
  for (int mt = 0; mt < 4; mt++)
    #pragma unroll
    for (int nt = 0; nt < 4; nt++)
      #pragma unroll
      for (int r = 0; r < 4; r++) {
        int m = wm * 64 + mt * 16 + q * 4 + r;
        int n = wn * 64 + nt * 16 + l16;
        cst[m * 136 + n] = f2bf(acc[mt][nt][r]);
      }
  __syncthreads();
  #pragma unroll
  for (int i = 0; i < 8; i++) {
    int idx = tid + i * 256;                // < 2048
    int row = idx >> 4, ch = idx & 15;
    uint4 v = *(const uint4*)((const char*)cst + row * 272 + ch * 16);
    *(uint4*)((char*)C + ((m0 + row) * NGATE + n0) * 2 + ch * 16) = v;
  }
}

// ---------------------------------------------------------------- Phase B
// 4 groups x 64 blocks x 256 threads. Group = 8 batches, full gate dim.
// Block m: hidden cols m*16..+16 => local gate cols n = G*16+j, G=0..3.
__global__ __launch_bounds__(256) void lstm_persistent(
    const unsigned short* __restrict__ xg,   // [16384][4096] bf16
    const unsigned short* __restrict__ whT,  // [4096][1024] bf16
    const float* __restrict__ bias,          // [4096]
    float* __restrict__ out,                 // [32][512][1024]
    unsigned short* ring,                    // 512 slots x 4 groups x [8][1024] bf16
    unsigned* flags) {                       // 256 @ 16B stride, group-major
  extern __shared__ char smem[];
  char* w_lds = smem + W_OFF_L;                    // [64 rows n][2048B k] +16B pad
  char* h_lds = smem + H_OFF_L;                    // [8 rows b][2048B k] +16B pad
  float* gates = (float*)(smem + G_OFF_L);         // [16][65] f32 (rows 8-15 dup)

  const int tid = threadIdx.x;
  const int lane = tid & 63, wv = tid >> 6, q = lane >> 4, l16 = lane & 15;
  const int g = blockIdx.x >> 6;                   // group 0..3
  const int m = blockIdx.x & 63;                   // member 0..63
  const int b_l = tid >> 4, j_l = tid & 15;        // EW mapping (tid<128)

  // pin Wh slice: LDS row n (= G*16+j) <- whT row G*1024 + m*16 + j
  for (int idx = tid; idx < 64 * 128; idx += 256) {
    int n = idx >> 7, ch = idx & 127;
    size_t gr = (size_t)(n >> 4) * 1024 + m * 16 + (n & 15);
    uint4 v = *(const uint4*)((const char*)whT + gr * 2048 + ch * 16);
    *(uint4*)(w_lds + n * 2064 + ch * 16) = v;
  }
  float bsr[4];
  #pragma unroll
  for (int G = 0; G < 4; G++) bsr[G] = bias[G * 1024 + m * 16 + j_l];
  float c_st = 0.f;
  const char* arow = h_lds + (l16 & 7) * 2064 + q * 16;   // rows 8-15 mirror 0-7
  const char* brow = w_lds + (wv * 16 + l16) * 2064 + q * 16;
  unsigned short* ring_g = ring + (size_t)g * 8192;       // 16KB group image
  unsigned* fl_g = flags + g * 64 * FLAG_STRIDE;
  __syncthreads();

  for (int t = 0; t < SLEN; t++) {
    // xg prefetch (no h dependency) — overlaps the flag wait
    unsigned short xgv[4];
    if (tid < 128) {
      const unsigned short* p =
          xg + ((size_t)(g * 8 + b_l) * 512 + t) * 4096 + m * 16 + j_l;
      xgv[0] = p[0]; xgv[1] = p[1024]; xgv[2] = p[2048]; xgv[3] = p[3072];
    }
    if (t > 0) {
      if (tid < 64) {
        const unsigned* fp = fl_g + tid * FLAG_STRIDE;
        while (__hip_atomic_load(fp, __ATOMIC_RELAXED, __HIP_MEMORY_SCOPE_AGENT) < (unsigned)t)
          __builtin_amdgcn_s_sleep(1);
      }
      __syncthreads();
      asm volatile("" ::: "memory");
      // gather group h image from ring slot t-1 with PLAIN coalesced dwordx4
      // (virgin addresses -> no stale L1/L2; producers wrote LLC; lane-
      //  contiguous 16B chunks -> 1KB/instruction, line-based, L2-shared)
      {
        const char* src = (const char*)(ring_g + (size_t)(t - 1) * SLOT_SHORTS);
        uint4 v0 = *(const uint4*)(src + tid * 16);
        uint4 v1 = *(const uint4*)(src + tid * 16 + 4096);
        uint4 v2 = *(const uint4*)(src + tid * 16 + 8192);
        uint4 v3 = *(const uint4*)(src + tid * 16 + 12288);
        int c0 = tid, c1 = tid + 256, c2 = tid + 512, c3 = tid + 768;
        *(uint4*)(h_lds + (c0 >> 7) * 2064 + (c0 & 127) * 16) = v0;
        *(uint4*)(h_lds + (c1 >> 7) * 2064 + (c1 & 127) * 16) = v1;
        *(uint4*)(h_lds + (c2 >> 7) * 2064 + (c2 & 127) * 16) = v2;
        *(uint4*)(h_lds + (c3 >> 7) * 2064 + (c3 & 127) * 16) = v3;
      }
    }
    __syncthreads();

    // gates[b][n] = sum_k h[b][k] * Wslice[k][n]; wave wv = N-tile wv
    f32x4_t acc0 = (f32x4_t){0.f, 0.f, 0.f, 0.f};
    f32x4_t acc1 = (f32x4_t){0.f, 0.f, 0.f, 0.f};
    if (t > 0) {
      #pragma unroll
      for (int kk = 0; kk < 32; kk += 2) {
        bf16x8_t a0 = *(const bf16x8_t*)(arow + kk * 64);
        bf16x8_t b0 = *(const bf16x8_t*)(brow + kk * 64);
        acc0 = __builtin_amdgcn_mfma_f32_16x16x32_bf16(a0, b0, acc0, 0, 0, 0);
        bf16x8_t a1 = *(const bf16x8_t*)(arow + kk * 64 + 64);
        bf16x8_t b1 = *(const bf16x8_t*)(brow + kk * 64 + 64);
        acc1 = __builtin_amdgcn_mfma_f32_16x16x32_bf16(a1, b1, acc1, 0, 0, 0);
      }
    }
    #pragma unroll
    for (int r = 0; r < 4; r++) {
      int bb = q * 4 + r;                          // rows 8-15 are duplicates
      gates[bb * 65 + wv * 16 + l16] = acc0[r] + acc1[r];
    }
    __syncthreads();

    // elementwise: 128 threads own (b_l, j_l)
    if (tid < 128) {
      float gi = gates[b_l * 65 + j_l]      + bsr[0] + bf2f(xgv[0]);
      float gf = gates[b_l * 65 + 16 + j_l] + bsr[1] + bf2f(xgv[1]);
      float gg = gates[b_l * 65 + 32 + j_l] + bsr[2] + bf2f(xgv[2]);
      float go = gates[b_l * 65 + 48 + j_l] + bsr[3] + bf2f(xgv[3]);
      float i_s = sigmoid_f(gi), f_s = sigmoid_f(gf);
      float g_t = tanh_f(gg), o_s = sigmoid_f(go);
      c_st = f_s * c_st + i_s * g_t;
      float h = o_s * tanh_f(c_st);
      // pack 4 cols into 8B via two shuffles; lanes j%4==0 store LLC-direct
      unsigned short hb = f2bf(h);
      unsigned other = __shfl_xor((unsigned)hb, 1);
      unsigned u = ((unsigned)hb & 0xffffu) | (other << 16);   // cols j, j+1
      unsigned u2 = __shfl_xor(u, 2);                          // cols j+2, j+3
      if ((j_l & 3) == 0) {
        ull_t v8 = (ull_t)u | ((ull_t)u2 << 32);
        ull_t* dst = (ull_t*)(ring_g + (size_t)t * SLOT_SHORTS +
                              b_l * 1024 + m * 16 + j_l);
        __hip_atomic_store(dst, v8, __ATOMIC_RELAXED, __HIP_MEMORY_SCOPE_AGENT);
      }
      out[((size_t)(g * 8 + b_l) * 512 + t) * 1024 + m * 16 + j_l] = h;
    }
    // drain own wave's stores; barrier = all waves drained; then flag
    asm volatile("s_waitcnt vmcnt(0)" ::: "memory");
    __syncthreads();
    if (tid == 0)
      __hip_atomic_store(fl_g + m * FLAG_STRIDE, (unsigned)(t + 1),
                         __ATOMIC_RELAXED, __HIP_MEMORY_SCOPE_AGENT);
  }
}

// ---------------------------------------------------------------- launcher
extern "C" void kernel_launch(void* const* d_in, const int* in_sizes, int n_in,
                              void* d_out, int out_size, void* d_ws, size_t ws_size,
                              hipStream_t stream) {
  const float* x    = (const float*)d_in[0];   // [32,512,1024]
  const float* wi   = (const float*)d_in[1];   // [1024,4096]
  const float* wh   = (const float*)d_in[2];   // [1024,4096]
  const float* bias = (const float*)d_in[3];   // [4096]
  float* out = (float*)d_out;

  char* ws = (char*)d_ws;
  unsigned short* xg   = (unsigned short*)(ws + XG_OFF);
  unsigned short* xb   = (unsigned short*)(ws + XB_OFF);   // dead after gemm_xg
  unsigned short* ring = (unsigned short*)(ws + RING_OFF); // overlays xb
  unsigned short* wiT  = (unsigned short*)(ws + WIT_OFF);
  unsigned short* whT  = (unsigned short*)(ws + WHT_OFF);
  unsigned* flags      = (unsigned*)(ws + FLAGS_OFF);

  (void)hipFuncSetAttribute((const void*)lstm_persistent,
                            hipFuncAttributeMaxDynamicSharedMemorySize,
                            LDS_TOTAL);

  conv_x_bf16<<<16384, 256, 0, stream>>>(x, xb);
  transpose_w_bf16<<<dim3(128, 32), dim3(32, 8), 0, stream>>>(wi, wiT);
  transpose_w_bf16<<<dim3(128, 32), dim3(32, 8), 0, stream>>>(wh, whT);
  init_ws<<<4, 256, 0, stream>>>(flags);
  gemm_xg<<<dim3(32, 128), 256, 34816, stream>>>(xb, wiT, xg);
  lstm_persistent<<<NBLK_B, 256, LDS_TOTAL, stream>>>(xg, whT, bias, out, ring, flags);
}

// Round 4
// 1930.458 us; speedup vs baseline: 2.0071x; 1.1383x over previous
//
#include <hip/hip_runtime.h>

// ---------------------------------------------------------------------------
// ManualLSTM: B=32, S=512, H=1024.
//   Phase A: xg = bf16(x) @ bf16(Wi)  -> bf16 [16384][4096]  (bias in phase B)
//   Phase B (R10 = R9 + W-in-VGPR + vmcnt(1) drain): persistent recurrence,
//     4 groups x 64 blocks. Group g owns batches 8g..8g+7 + full gate dim;
//     block m owns hidden cols m*16..+16 (64 gate cols).
//     - Wh B-fragments pinned in VGPRs (32 bf16x8/lane = 128 VGPR), loaded
//       ONCE from global; empty volatile asm "+v" tie after the loads blocks
//       the R8 failure mode (compiler sinking the loads into the t-loop).
//       K-loop = 32 ds_read_b128 (A only) + 32 MFMA -> LDS traffic halved.
//     - h exchange via NEVER-REUSED ring (512 slots x 4 groups x 16KB = 32MB,
//       overlays dead xb region). Producers: shfl-packed 8B agent-scope (LLC)
//       atomic stores. Consumers: PLAIN coalesced dwordx4 gather into LDS
//       (virgin addresses -> no stale L1/L2; R8/R9-validated).
//     - Drain: ring store issued FIRST, out[] store second, then
//       s_waitcnt vmcnt(1): waits only the (oldest) ring store; the HBM
//       out-store ack leaves the critical path. Then barrier + relaxed flag
//       (R3/R6/R9-validated protocol otherwise unchanged).
//     - LDS now 20.7KB static (h image 8x2064 + gates).
// ---------------------------------------------------------------------------

typedef __attribute__((ext_vector_type(4))) float f32x4_t;
typedef __attribute__((ext_vector_type(8))) short bf16x8_t;
typedef unsigned long long ull_t;

#define HID   1024
#define SLEN  512
#define NGATE 4096

// ws layout (bytes)
#define XG_OFF    0ULL                      // 16384*4096*2 = 134217728
#define RING_OFF  134217728ULL              // 512*4*16384  = 33554432 (old xb)
#define WIT_OFF   167772160ULL              // 4096*1024*2  = 8388608
#define WHT_OFF   176160768ULL              // 4096*1024*2  = 8388608
#define FLAGS_OFF 184680448ULL              // 256 flags * 16B stride = 4096B
// xb (phase-A bf16 x) shares the RING region: gemm_xg reads it fully before
// lstm_persistent writes the ring (same stream, sequential dispatches).
#define XB_OFF    RING_OFF

#define NBLK_B      256                     // 4 groups x 64 blocks
#define FLAG_STRIDE 4                       // dwords (16B)
#define SLOT_SHORTS 32768                   // 4 groups * 8192 shorts = 64KB/slot

__device__ __forceinline__ unsigned short f2bf(float f) {
  unsigned u = __float_as_uint(f);
  u += 0x7fffu + ((u >> 16) & 1u);          // round-nearest-even
  return (unsigned short)(u >> 16);
}
__device__ __forceinline__ float bf2f(unsigned short u) {
  return __uint_as_float(((unsigned)u) << 16);
}
__device__ __forceinline__ float fast_rcp(float x) { return __builtin_amdgcn_rcpf(x); }
__device__ __forceinline__ float sigmoid_f(float x) { return fast_rcp(1.f + __expf(-x)); }
__device__ __forceinline__ float tanh_f(float x) { return 1.f - 2.f * fast_rcp(1.f + __expf(2.f * x)); }

// ---------------------------------------------------------------- converters
__global__ __launch_bounds__(256) void conv_x_bf16(const float* __restrict__ in,
                                                   unsigned short* __restrict__ out) {
  size_t i = (size_t)blockIdx.x * 256 + threadIdx.x;
  const float4* p = (const float4*)in;
  float4 v = p[i];
  ushort4 o;
  o.x = f2bf(v.x); o.y = f2bf(v.y); o.z = f2bf(v.z); o.w = f2bf(v.w);
  ((ushort4*)out)[i] = o;
}

// in: fp32 [1024][4096]  -> out: bf16 [4096][1024]  (out[n][k] = in[k][n])
__global__ void transpose_w_bf16(const float* __restrict__ in,
                                 unsigned short* __restrict__ out) {
  __shared__ float tile[32][33];
  int tx = threadIdx.x, ty = threadIdx.y;        // block (32, 8)
  int n0 = blockIdx.x * 32, k0 = blockIdx.y * 32;
  #pragma unroll
  for (int i = 0; i < 4; i++)
    tile[ty + 8 * i][tx] = in[(size_t)(k0 + ty + 8 * i) * NGATE + n0 + tx];
  __syncthreads();
  #pragma unroll
  for (int i = 0; i < 4; i++)
    out[(size_t)(n0 + ty + 8 * i) * HID + k0 + tx] = f2bf(tile[tx][ty + 8 * i]);
}

__global__ void init_ws(unsigned* __restrict__ flags) {
  int i = (int)blockIdx.x * 256 + threadIdx.x;   // 1024 threads
  if (i < NBLK_B * FLAG_STRIDE) flags[i] = 0u;
}

// ---------------------------------------------------------------- Phase A
// C[16384][4096] bf16 = A[16384][1024] bf16  x  BT[4096][1024] bf16
__global__ __launch_bounds__(256) void gemm_xg(const unsigned short* __restrict__ A,
                                               const unsigned short* __restrict__ BT,
                                               unsigned short* __restrict__ C) {
  extern __shared__ char smem[];
  char* As = smem;                 // 128 rows * 80B (32 bf16 + 16B pad)
  char* Bs = smem + 10240;
  const int tid = threadIdx.x;
  const int lane = tid & 63, w = tid >> 6, q = lane >> 4, l16 = lane & 15;
  const int wm = w & 1, wn = w >> 1;
  const size_t m0 = (size_t)blockIdx.y * 128, n0 = (size_t)blockIdx.x * 128;

  f32x4_t acc[4][4];
  #pragma unroll
  for (int i = 0; i < 4; i++)
    #pragma unroll
    for (int j = 0; j < 4; j++) acc[i][j] = (f32x4_t){0.f, 0.f, 0.f, 0.f};

  for (int kk = 0; kk < 32; kk++) {
    const int k0 = kk * 32;
    #pragma unroll
    for (int h = 0; h < 2; h++) {
      int idx = tid + h * 256;              // 0..511
      int r = idx >> 2, ch = idx & 3;
      uint4 va = *(const uint4*)((const char*)A + ((m0 + r) * HID + k0) * 2 + ch * 16);
      *(uint4*)(As + r * 80 + ch * 16) = va;
      uint4 vb = *(const uint4*)((const char*)BT + ((n0 + r) * HID + k0) * 2 + ch * 16);
      *(uint4*)(Bs + r * 80 + ch * 16) = vb;
    }
    __syncthreads();
    bf16x8_t af[4], bf[4];
    #pragma unroll
    for (int mt = 0; mt < 4; mt++)
      af[mt] = *(const bf16x8_t*)(As + (wm * 64 + mt * 16 + l16) * 80 + q * 16);
    #pragma unroll
    for (int nt = 0; nt < 4; nt++)
      bf[nt] = *(const bf16x8_t*)(Bs + (wn * 64 + nt * 16 + l16) * 80 + q * 16);
    #pragma unroll
    for (int mt = 0; mt < 4; mt++)
      #pragma unroll
      for (int nt = 0; nt < 4; nt++)
        acc[mt][nt] = __builtin_amdgcn_mfma_f32_16x16x32_bf16(af[mt], bf[nt], acc[mt][nt], 0, 0, 0);
    __syncthreads();
  }

  // epilogue: stage C tile (bf16 [128][136]) through LDS for coalesced stores
  unsigned short* cst = (unsigned short*)smem;
  #pragma unroll
  for (int mt = 0; mt < 4; mt++)
    #pragma unroll
    for (int nt = 0; nt < 4; nt++)
      #pragma unroll
      for (int r = 0; r < 4; r++) {
        int m = wm * 64 + mt * 16 + q * 4 + r;
        int n = wn * 64 + nt * 16 + l16;
        cst[m * 136 + n] = f2bf(acc[mt][nt][r]);
      }
  __syncthreads();
  #pragma unroll
  for (int i = 0; i < 8; i++) {
    int idx = tid + i * 256;                // < 2048
    int row = idx >> 4, ch = idx & 15;
    uint4 v = *(const uint4*)((const char*)cst + row * 272 + ch * 16);
    *(uint4*)((char*)C + ((m0 + row) * NGATE + n0) * 2 + ch * 16) = v;
  }
}

// ---------------------------------------------------------------- Phase B
// 4 groups x 64 blocks x 256 threads. Group = 8 batches, full gate dim.
// Block m: hidden cols m*16..+16 => local gate cols n = G*16+j, G=0..3.
__global__ __launch_bounds__(256, 1) void lstm_persistent(
    const unsigned short* __restrict__ xg,   // [16384][4096] bf16
    const unsigned short* __restrict__ whT,  // [4096][1024] bf16
    const float* __restrict__ bias,          // [4096]
    float* __restrict__ out,                 // [32][512][1024]
    unsigned short* ring,                    // 512 slots x 4 groups x [8][1024] bf16
    unsigned* flags) {                       // 256 @ 16B stride, group-major
  __shared__ __align__(16) char h_lds[8 * 2064];   // [8 rows b][2048B k] +16B pad
  __shared__ float gates[16 * 65];                 // [16][65] f32 (rows 8-15 dup)

  const int tid = threadIdx.x;
  const int lane = tid & 63, wv = tid >> 6, q = lane >> 4, l16 = lane & 15;
  const int g = blockIdx.x >> 6;                   // group 0..3
  const int m = blockIdx.x & 63;                   // member 0..63
  const int b_l = tid >> 4, j_l = tid & 15;        // EW mapping (tid<128)

  // pin Wh B-fragments in VGPRs: wave wv owns gate cols wv*1024 + m*16 + l16.
  // Loaded once; the volatile asm "+v" ties make the values asm-defined so
  // the compiler cannot re-sink the loads into the t-loop (R8 failure mode).
  bf16x8_t bfr[32];
  {
    const char* wrow = (const char*)whT +
        ((size_t)(wv * 1024 + m * 16 + l16) * HID) * 2 + q * 16;
    #pragma unroll
    for (int kk = 0; kk < 32; kk++)
      bfr[kk] = *(const bf16x8_t*)(wrow + kk * 64);
    #pragma unroll
    for (int kk = 0; kk < 32; kk++)
      asm volatile("" : "+v"(bfr[kk]));
  }
  float bsr[4];
  #pragma unroll
  for (int G = 0; G < 4; G++) bsr[G] = bias[G * 1024 + m * 16 + j_l];
  float c_st = 0.f;
  const char* arow = h_lds + (l16 & 7) * 2064 + q * 16;   // rows 8-15 mirror 0-7
  unsigned short* ring_g = ring + (size_t)g * 8192;       // 16KB group image
  unsigned* fl_g = flags + g * 64 * FLAG_STRIDE;

  for (int t = 0; t < SLEN; t++) {
    // xg prefetch (no h dependency) — overlaps the flag wait
    unsigned short xgv[4];
    if (tid < 128) {
      const unsigned short* p =
          xg + ((size_t)(g * 8 + b_l) * 512 + t) * 4096 + m * 16 + j_l;
      xgv[0] = p[0]; xgv[1] = p[1024]; xgv[2] = p[2048]; xgv[3] = p[3072];
    }
    if (t > 0) {
      if (tid < 64) {
        const unsigned* fp = fl_g + tid * FLAG_STRIDE;
        while (__hip_atomic_load(fp, __ATOMIC_RELAXED, __HIP_MEMORY_SCOPE_AGENT) < (unsigned)t)
          __builtin_amdgcn_s_sleep(1);
      }
      __syncthreads();
      asm volatile("" ::: "memory");
      // gather group h image from ring slot t-1 with PLAIN coalesced dwordx4
      // (virgin addresses -> no stale L1/L2; producers wrote LLC; lane-
      //  contiguous 16B chunks -> 1KB/instruction, line-based, L2-shared)
      {
        const char* src = (const char*)(ring_g + (size_t)(t - 1) * SLOT_SHORTS);
        uint4 v0 = *(const uint4*)(src + tid * 16);
        uint4 v1 = *(const uint4*)(src + tid * 16 + 4096);
        uint4 v2 = *(const uint4*)(src + tid * 16 + 8192);
        uint4 v3 = *(const uint4*)(src + tid * 16 + 12288);
        int c0 = tid, c1 = tid + 256, c2 = tid + 512, c3 = tid + 768;
        *(uint4*)(h_lds + (c0 >> 7) * 2064 + (c0 & 127) * 16) = v0;
        *(uint4*)(h_lds + (c1 >> 7) * 2064 + (c1 & 127) * 16) = v1;
        *(uint4*)(h_lds + (c2 >> 7) * 2064 + (c2 & 127) * 16) = v2;
        *(uint4*)(h_lds + (c3 >> 7) * 2064 + (c3 & 127) * 16) = v3;
      }
    }
    __syncthreads();

    // gates[b][n] = sum_k h[b][k] * Wslice[k][n]; wave wv = N-tile wv.
    // B comes from pinned VGPRs; only A is read from LDS (32 ds_read_b128).
    f32x4_t acc0 = (f32x4_t){0.f, 0.f, 0.f, 0.f};
    f32x4_t acc1 = (f32x4_t){0.f, 0.f, 0.f, 0.f};
    if (t > 0) {
      #pragma unroll
      for (int kk = 0; kk < 32; kk += 2) {
        bf16x8_t a0 = *(const bf16x8_t*)(arow + kk * 64);
        bf16x8_t a1 = *(const bf16x8_t*)(arow + kk * 64 + 64);
        acc0 = __builtin_amdgcn_mfma_f32_16x16x32_bf16(a0, bfr[kk], acc0, 0, 0, 0);
        acc1 = __builtin_amdgcn_mfma_f32_16x16x32_bf16(a1, bfr[kk + 1], acc1, 0, 0, 0);
      }
    }
    #pragma unroll
    for (int r = 0; r < 4; r++) {
      int bb = q * 4 + r;                          // rows 8-15 are duplicates
      gates[bb * 65 + wv * 16 + l16] = acc0[r] + acc1[r];
    }
    __syncthreads();

    // elementwise: 128 threads own (b_l, j_l)
    if (tid < 128) {
      float gi = gates[b_l * 65 + j_l]      + bsr[0] + bf2f(xgv[0]);
      float gf = gates[b_l * 65 + 16 + j_l] + bsr[1] + bf2f(xgv[1]);
      float gg = gates[b_l * 65 + 32 + j_l] + bsr[2] + bf2f(xgv[2]);
      float go = gates[b_l * 65 + 48 + j_l] + bsr[3] + bf2f(xgv[3]);
      float i_s = sigmoid_f(gi), f_s = sigmoid_f(gf);
      float g_t = tanh_f(gg), o_s = sigmoid_f(go);
      c_st = f_s * c_st + i_s * g_t;
      float h = o_s * tanh_f(c_st);
      // pack 4 cols into 8B via two shuffles; lanes j%4==0 store LLC-direct.
      // Ring store issued FIRST (oldest) so vmcnt(1) below waits only it.
      unsigned short hb = f2bf(h);
      unsigned other = __shfl_xor((unsigned)hb, 1);
      unsigned u = ((unsigned)hb & 0xffffu) | (other << 16);   // cols j, j+1
      unsigned u2 = __shfl_xor(u, 2);                          // cols j+2, j+3
      if ((j_l & 3) == 0) {
        ull_t v8 = (ull_t)u | ((ull_t)u2 << 32);
        ull_t* dst = (ull_t*)(ring_g + (size_t)t * SLOT_SHORTS +
                              b_l * 1024 + m * 16 + j_l);
        __hip_atomic_store(dst, v8, __ATOMIC_RELAXED, __HIP_MEMORY_SCOPE_AGENT);
      }
      asm volatile("" ::: "memory");   // keep out-store AFTER ring store
      out[((size_t)(g * 8 + b_l) * 512 + t) * 1024 + m * 16 + j_l] = h;
    }
    // drain the ring store only (oldest); out[] HBM ack stays off the path
    asm volatile("s_waitcnt vmcnt(1)" ::: "memory");
    __syncthreads();
    if (tid == 0)
      __hip_atomic_store(fl_g + m * FLAG_STRIDE, (unsigned)(t + 1),
                         __ATOMIC_RELAXED, __HIP_MEMORY_SCOPE_AGENT);
  }
}

// ---------------------------------------------------------------- launcher
extern "C" void kernel_launch(void* const* d_in, const int* in_sizes, int n_in,
                              void* d_out, int out_size, void* d_ws, size_t ws_size,
                              hipStream_t stream) {
  const float* x    = (const float*)d_in[0];   // [32,512,1024]
  const float* wi   = (const float*)d_in[1];   // [1024,4096]
  const float* wh   = (const float*)d_in[2];   // [1024,4096]
  const float* bias = (const float*)d_in[3];   // [4096]
  float* out = (float*)d_out;

  char* ws = (char*)d_ws;
  unsigned short* xg   = (unsigned short*)(ws + XG_OFF);
  unsigned short* xb   = (unsigned short*)(ws + XB_OFF);   // dead after gemm_xg
  unsigned short* ring = (unsigned short*)(ws + RING_OFF); // overlays xb
  unsigned short* wiT  = (unsigned short*)(ws + WIT_OFF);
  unsigned short* whT  = (unsigned short*)(ws + WHT_OFF);
  unsigned* flags      = (unsigned*)(ws + FLAGS_OFF);

  conv_x_bf16<<<16384, 256, 0, stream>>>(x, xb);
  transpose_w_bf16<<<dim3(128, 32), dim3(32, 8), 0, stream>>>(wi, wiT);
  transpose_w_bf16<<<dim3(128, 32), dim3(32, 8), 0, stream>>>(wh, whT);
  init_ws<<<4, 256, 0, stream>>>(flags);
  gemm_xg<<<dim3(32, 128), 256, 34816, stream>>>(xb, wiT, xg);
  lstm_persistent<<<NBLK_B, 256, 0, stream>>>(xg, whT, bias, out, ring, flags);
}